// Round 15
// baseline (117.667 us; speedup 1.0000x reference)
//
#include <hip/hip_runtime.h>
#include <hip/hip_bf16.h>

// Problem constants (B=2, T=4096, D=1024, H=16, HD=64, W=16)
#define D_MODEL 1024
#define SEQ_T   4096
#define NBATCH  2
#define NHEADS  16
#define HEAD_D  64
#define WIN     16

typedef __attribute__((ext_vector_type(8))) short bf16x8;           // MFMA A/B frag
typedef __attribute__((ext_vector_type(8))) unsigned short u16x8;   // 16B bf16 load
typedef __attribute__((ext_vector_type(4))) float f32x4;            // MFMA C/D frag

__device__ __forceinline__ unsigned short f2bf(float f) {
  union { float f; unsigned int u; } v; v.f = f;
  unsigned int r = v.u + 0x7fffu + ((v.u >> 16) & 1u);  // RNE
  return (unsigned short)(r >> 16);
}
__device__ __forceinline__ float bf2f(unsigned short u) {
  union { unsigned int u; float f; } v; v.u = ((unsigned int)u) << 16;
  return v.f;
}

#define SBAR() __builtin_amdgcn_s_barrier()
#define LGKM0() asm volatile("s_waitcnt lgkmcnt(0)" ::: "memory")
#define LGKM8() asm volatile("s_waitcnt lgkmcnt(8)" ::: "memory")
#define VMC(n) asm volatile("s_waitcnt vmcnt(" #n ")" ::: "memory")

// ---------------------------------------------------------------- merged cast kernel
__global__ __launch_bounds__(256) void cast_all(const float4* __restrict__ x,
                                                const float4* __restrict__ wq,
                                                const float4* __restrict__ wkv,
                                                const float4* __restrict__ wo,
                                                ushort* __restrict__ xb,
                                                ushort* __restrict__ wb) {
  int i = blockIdx.x * 256 + threadIdx.x;  // 0..3145727 float4 units
  float4 v;
  ushort* dst;
  if (i < 2097152) {
    v = x[i];
    dst = xb + (size_t)i * 4;
  } else {
    int j = i - 2097152;  // 0..1048575
    const float4* src;
    int off;
    if (j < 262144) { src = wq; off = 0; }
    else if (j < 786432) { src = wkv; off = 262144; }
    else { src = wo; off = 786432; }
    v = src[j - off];
    dst = wb + (size_t)j * 4;
  }
  ushort4 o;
  o.x = f2bf(v.x); o.y = f2bf(v.y); o.z = f2bf(v.z); o.w = f2bf(v.w);
  *(ushort4*)dst = o;
}

// ---------------------------------------------------------------- GEMM1: 128x192, 8 waves, 2 blocks/CU
// R13 shape + doubled TLP: 512 thr = 8 waves (2M x 4N), per-wave 64 rows x 48 cols
// (acc[4][3], 24 MFMA/K-tile). LDS 80KiB unchanged -> 2 blocks/CU = 16 waves/CU = 4/SIMD.
// 3 phases/K-tile, chunk-XOR swizzle both-sides:
//   p1: read A(8)+B[0](2); stage B(t+1)[3]; lgkm8; SBAR; lgkm0; 8 MFMA; SBAR
//   p2: read B[1](2);                        SBAR; lgkm0; 8 MFMA; SBAR
//   p3: read B[2](2);      stage A(t+2)[2]; vmcnt(2); SBAR; lgkm0; 8 MFMA; SBAR
// Per-wave FIFO (5 loads/thread/K-tile: 3B + 2A): at p3, outstanding = A(t+1)2 + B(t+1)3 +
// A(t+2)2 = 7 -> vmcnt(2) retires tile t+1, leaves A(t+2). Prologue A0(2),B0(3),A1(2)=7 ✓.
// Region safety: B(t+1) dest held B(t-1), last read p3(t-1) [exit barrier]; A(t+2) dest
// holds A(t), read only at p1(t) [exit barrier]. Tail clamps restage identical bytes.
// __launch_bounds__(512,4): 4 waves/SIMD -> VGPR cap 128 (est ~110).
__global__ __launch_bounds__(512, 4) void gemm1_8w2b(const ushort* __restrict__ A,
                                                     const ushort* __restrict__ Bt,
                                                     ushort* __restrict__ C,
                                                     int M, int N, int K) {
  extern __shared__ char smem[];  // 81920 bytes
  const int NTK = K >> 6;
  const int tid = threadIdx.x;
  const int wid = tid >> 6;   // 0..7
  const int lane = tid & 63;
  const int lin = blockIdx.y * 16 + blockIdx.x;     // 0..1023
  const int swz = (lin & 7) * 128 + (lin >> 3);     // bijective (1024 % 8 == 0)
  const int m0 = (swz >> 4) * 128;
  const int n0 = (swz & 15) * 192;

  // staging lane geometry (pre-swizzled source chunk; involution c ^= row&7)
  const int l8 = lane >> 3;
  const int lchunk = (lane & 7) ^ (l8 & 7);
  const ushort* pA = A + (size_t)(m0 + wid * 8 + l8) * K + lchunk * 8;
  const ushort* pB = Bt + (size_t)(n0 + wid * 8 + l8) * K + lchunk * 8;

// A tile 128x64 = 16 segs of 8 rows; 512 thr cover 64 rows/issue -> 2 issues (j=0,1).
#define SA(kt, db)                                                                         \
  {                                                                                        \
    _Pragma("unroll") for (int j = 0; j < 2; ++j) {                                        \
      const ushort* gp = pA + (size_t)(j * 64) * K + (size_t)(kt) * 64;                    \
      char* lp = smem + (db) * 16384 + (j * 8 + wid) * 1024;                               \
      __builtin_amdgcn_global_load_lds((const __attribute__((address_space(1))) void*)gp,  \
                                       (__attribute__((address_space(3))) void*)lp, 16, 0, 0); \
    }                                                                                      \
  }
// B tile 192x64 = 24 segs; 3 issues (j=0..2).
#define SB(kt, db)                                                                         \
  {                                                                                        \
    _Pragma("unroll") for (int j = 0; j < 3; ++j) {                                        \
      const ushort* gp = pB + (size_t)(j * 64) * K + (size_t)(kt) * 64;                    \
      char* lp = smem + 32768 + (db) * 24576 + (j * 8 + wid) * 1024;                       \
      __builtin_amdgcn_global_load_lds((const __attribute__((address_space(1))) void*)gp,  \
                                       (__attribute__((address_space(3))) void*)lp, 16, 0, 0); \
    }                                                                                      \
  }

  // compute-side lane geometry: 8 waves = 2M x 4N; per-wave 64 rows x 48 cols
  const int fr = lane & 15;
  const int g = lane >> 4;
  const int wr = wid >> 2;   // 0..1 (64-row band)
  const int wc = wid & 3;    // 0..3 (48-col band)
  int aRow[4], bRow[3], ch[2];
#pragma unroll
  for (int mi = 0; mi < 4; ++mi) aRow[mi] = (wr * 64 + mi * 16 + fr) * 128;
#pragma unroll
  for (int j = 0; j < 3; ++j) bRow[j] = (wc * 48 + j * 16 + fr) * 128;
#pragma unroll
  for (int kk = 0; kk < 2; ++kk) ch[kk] = ((kk * 4 + g) ^ (fr & 7)) * 16;

  f32x4 acc[4][3];
#pragma unroll
  for (int mi = 0; mi < 4; ++mi)
#pragma unroll
    for (int j = 0; j < 3; ++j) acc[mi][j] = (f32x4){0.f, 0.f, 0.f, 0.f};

  bf16x8 a[4][2], b[2];

#define RD_A(db)                                                               \
  _Pragma("unroll") for (int mi = 0; mi < 4; ++mi)                             \
    _Pragma("unroll") for (int kk = 0; kk < 2; ++kk)                           \
      a[mi][kk] = *(const bf16x8*)(smem + (db) * 16384 + aRow[mi] + ch[kk]);
#define RD_B(db, nh)                                                           \
  _Pragma("unroll") for (int kk = 0; kk < 2; ++kk)                             \
    b[kk] = *(const bf16x8*)(smem + 32768 + (db) * 24576 + bRow[nh] + ch[kk]);
#define MM(nh)                                                                 \
  __builtin_amdgcn_s_setprio(1);                                               \
  _Pragma("unroll") for (int kk = 0; kk < 2; ++kk)                             \
    _Pragma("unroll") for (int mi = 0; mi < 4; ++mi)                           \
      acc[mi][nh] = __builtin_amdgcn_mfma_f32_16x16x32_bf16(                   \
          a[mi][kk], b[kk], acc[mi][nh], 0, 0, 0);                             \
  __builtin_amdgcn_s_setprio(0);

  // ---- prologue: A(0),B(0),A(1) = 7 loads/thread; vmcnt(2) -> tile0 arrived
  SA(0, 0); SB(0, 0); SA(1, 1);
  VMC(2);
  SBAR();

#pragma unroll 1
  for (int t = 0; t < NTK; ++t) {
    const int db = t & 1;
    const int t1 = (t + 1 < NTK) ? t + 1 : NTK - 1;
    const int t2 = (t + 2 < NTK) ? t + 2 : NTK - 1;
    const int d1 = t1 & 1, d2 = t2 & 1;

    // ---- p1: read A(8) + B[0](2); stage B(t+1)
    RD_A(db); RD_B(db, 0);
    SB(t1, d1);
    LGKM8();
    SBAR(); LGKM0();
    MM(0);
    SBAR();

    // ---- p2: read B[1](2)
    RD_B(db, 1);
    SBAR(); LGKM0();
    MM(1);
    SBAR();

    // ---- p3: read B[2](2); stage A(t+2); counted vmcnt
    RD_B(db, 2);
    SA(t2, d2);
    VMC(2);
    SBAR(); LGKM0();
    MM(2);
    SBAR();
  }

  // ---- epilogue: C/D layout col=lane&15, row=(lane>>4)*4+r
  const int cc = lane & 15;
  const int cr4 = (lane >> 4) * 4;
#pragma unroll
  for (int mi = 0; mi < 4; ++mi)
#pragma unroll
    for (int j = 0; j < 3; ++j)
#pragma unroll
      for (int r = 0; r < 4; ++r) {
        int row = m0 + wr * 64 + mi * 16 + cr4 + r;
        int col = n0 + wc * 48 + j * 16 + cc;
        C[(size_t)row * N + col] = f2bf(acc[mi][j][r]);
      }
#undef SA
#undef SB
#undef RD_A
#undef RD_B
#undef MM
}

// ---------------------------------------------------------------- GEMM2: 128x128, 4 waves, 2 blocks/CU
// (R14 — unchanged.)
__global__ __launch_bounds__(256, 2) void gemm2_2pc(const ushort* __restrict__ A,
                                                    const ushort* __restrict__ Bt,
                                                    const ushort* __restrict__ residb,
                                                    ushort* __restrict__ Yb,
                                                    int M, int N, int K) {
  extern __shared__ char smem[];  // 65536 bytes
  const int NTK = K >> 6;
  const int tid = threadIdx.x;
  const int wid = tid >> 6;   // 0..3
  const int lane = tid & 63;
  const int lin = blockIdx.y * 8 + blockIdx.x;      // 0..511
  const int swz = (lin & 7) * 64 + (lin >> 3);      // bijective (512 % 8 == 0)
  const int m0 = (swz >> 3) * 128;
  const int n0 = (swz & 7) * 128;

  const int l8 = lane >> 3;
  const int lchunk = (lane & 7) ^ (l8 & 7);
  const ushort* pA = A + (size_t)(m0 + wid * 8 + l8) * K + lchunk * 8;
  const ushort* pB = Bt + (size_t)(n0 + wid * 8 + l8) * K + lchunk * 8;

#define SA2(kt, db)                                                                        \
  {                                                                                        \
    _Pragma("unroll") for (int j = 0; j < 4; ++j) {                                        \
      const ushort* gp = pA + (size_t)(j * 32) * K + (size_t)(kt) * 64;                    \
      char* lp = smem + (db) * 16384 + (j * 4 + wid) * 1024;                               \
      __builtin_amdgcn_global_load_lds((const __attribute__((address_space(1))) void*)gp,  \
                                       (__attribute__((address_space(3))) void*)lp, 16, 0, 0); \
    }                                                                                      \
  }
#define SB2(kt, db)                                                                        \
  {                                                                                        \
    _Pragma("unroll") for (int j = 0; j < 4; ++j) {                                        \
      const ushort* gp = pB + (size_t)(j * 32) * K + (size_t)(kt) * 64;                    \
      char* lp = smem + 32768 + (db) * 16384 + (j * 4 + wid) * 1024;                       \
      __builtin_amdgcn_global_load_lds((const __attribute__((address_space(1))) void*)gp,  \
                                       (__attribute__((address_space(3))) void*)lp, 16, 0, 0); \
    }                                                                                      \
  }

  const int fr = lane & 15;
  const int g = lane >> 4;
  const int wr = wid >> 1;   // 0..1
  const int wc = wid & 1;    // 0..1
  int aRow[4], bRow[4], ch[2];
#pragma unroll
  for (int mi = 0; mi < 4; ++mi) aRow[mi] = (wr * 64 + mi * 16 + fr) * 128;
#pragma unroll
  for (int j = 0; j < 4; ++j) bRow[j] = (wc * 64 + j * 16 + fr) * 128;
#pragma unroll
  for (int kk = 0; kk < 2; ++kk) ch[kk] = ((kk * 4 + g) ^ (fr & 7)) * 16;

  f32x4 acc[4][4];
#pragma unroll
  for (int mi = 0; mi < 4; ++mi)
#pragma unroll
    for (int j = 0; j < 4; ++j) acc[mi][j] = (f32x4){0.f, 0.f, 0.f, 0.f};

  bf16x8 a[4][2], b[2][2];

#define RD_A2(db)                                                              \
  _Pragma("unroll") for (int mi = 0; mi < 4; ++mi)                             \
    _Pragma("unroll") for (int kk = 0; kk < 2; ++kk)                           \
      a[mi][kk] = *(const bf16x8*)(smem + (db) * 16384 + aRow[mi] + ch[kk]);
#define RD_B2(db, nh)                                                          \
  _Pragma("unroll") for (int ni = 0; ni < 2; ++ni)                             \
    _Pragma("unroll") for (int kk = 0; kk < 2; ++kk)                           \
      b[ni][kk] = *(const bf16x8*)(smem + 32768 + (db) * 16384 +               \
                                   bRow[(nh) * 2 + ni] + ch[kk]);
#define MM2(nh)                                                                \
  __builtin_amdgcn_s_setprio(1);                                               \
  _Pragma("unroll") for (int kk = 0; kk < 2; ++kk)                             \
    _Pragma("unroll") for (int mi = 0; mi < 4; ++mi)                           \
      _Pragma("unroll") for (int ni = 0; ni < 2; ++ni)                         \
        acc[mi][(nh) * 2 + ni] = __builtin_amdgcn_mfma_f32_16x16x32_bf16(      \
            a[mi][kk], b[ni][kk], acc[mi][(nh) * 2 + ni], 0, 0, 0);            \
  __builtin_amdgcn_s_setprio(0);

  SA2(0, 0); SB2(0, 0); SA2(1, 1);
  VMC(4);
  SBAR();

#pragma unroll 1
  for (int t = 0; t < NTK; ++t) {
    const int db = t & 1;
    const int t1 = (t + 1 < NTK) ? t + 1 : NTK - 1;
    const int t2 = (t + 2 < NTK) ? t + 2 : NTK - 1;
    const int d1 = t1 & 1, d2 = t2 & 1;

    RD_A2(db); RD_B2(db, 0);
    SB2(t1, d1);
    LGKM8();
    SBAR(); LGKM0();
    MM2(0);
    SBAR();

    RD_B2(db, 1);
    SA2(t2, d2);
    VMC(4);
    SBAR(); LGKM0();
    MM2(1);
    SBAR();
  }

  const int cc = lane & 15;
  const int cr4 = (lane >> 4) * 4;
#pragma unroll
  for (int mi = 0; mi < 4; ++mi)
#pragma unroll
    for (int j = 0; j < 4; ++j)
#pragma unroll
      for (int r = 0; r < 4; ++r) {
        int row = m0 + wr * 64 + mi * 16 + cr4 + r;
        int col = n0 + wc * 64 + j * 16 + cc;
        size_t idx = (size_t)row * N + col;
        Yb[idx] = f2bf(acc[mi][j][r] + bf2f(residb[idx]));
      }
#undef SA2
#undef SB2
#undef RD_A2
#undef RD_B2
#undef MM2
}

// ---------------------------------------------------------------- sliding-window attention (MFMA band)
__global__ __launch_bounds__(256) void attn_win_mfma(const ushort* __restrict__ qkv,
                                                     ushort* __restrict__ msg) {
  __shared__ ushort Ks[80][72];
  __shared__ ushort Vt[64][88];
  __shared__ ushort Ps[4][16][40];

  const int tile = blockIdx.x;
  const int h = blockIdx.y;
  const int b = blockIdx.z;
  const int t0 = tile * 64;
  const size_t rowbase = (size_t)b * SEQ_T;
  const int tid = threadIdx.x;
  const int wave = tid >> 6;
  const int lane = tid & 63;

  for (int chunk = tid; chunk < 1280; chunk += 256) {
    int r = chunk >> 4;
    int c = (chunk & 15) * 8;
    int t = t0 - 16 + r;
    u16x8 u = {0, 0, 0, 0, 0, 0, 0, 0};
    if (t >= 0)
      u = *(const u16x8*)(qkv + (rowbase + t) * 3072 + 1024 + (size_t)h * 128 + c);
    if (c < 64) {
      *(u16x8*)&Ks[r][c] = u;
    } else {
      int d0 = c - 64;
#pragma unroll
      for (int j = 0; j < 8; ++j) Vt[d0 + j][r] = u[j];
    }
  }
  __syncthreads();

  const int fr = lane & 15;
  const int g = lane >> 4;
  const int rbase = wave * 16;

  bf16x8 qa[2];
#pragma unroll
  for (int kk = 0; kk < 2; ++kk)
    qa[kk] = *(const bf16x8*)(qkv + (rowbase + t0 + wave * 16 + fr) * 3072 +
                              (size_t)h * 64 + kk * 32 + g * 8);

  f32x4 sacc[2];
  sacc[0] = (f32x4){0.f, 0.f, 0.f, 0.f};
  sacc[1] = (f32x4){0.f, 0.f, 0.f, 0.f};
#pragma unroll
  for (int kk = 0; kk < 2; ++kk) {
#pragma unroll
    for (int nt = 0; nt < 2; ++nt) {
      bf16x8 kb = *(const bf16x8*)&Ks[rbase + nt * 16 + fr][kk * 32 + g * 8];
      sacc[nt] = __builtin_amdgcn_mfma_f32_16x16x32_bf16(qa[kk], kb, sacc[nt], 0, 0, 0);
    }
  }

#pragma unroll
  for (int nt = 0; nt < 2; ++nt) {
    int tk = t0 - 16 + rbase + nt * 16 + fr;
#pragma unroll
    for (int reg = 0; reg < 4; ++reg) {
      int t = t0 + wave * 16 + g * 4 + reg;
      float tau = 0.f;
      if (tk >= 0 && tk >= t - WIN && tk <= t - 1)
        tau = 1.f / (1.f + __expf(-sacc[nt][reg] * 0.125f));
      Ps[wave][g * 4 + reg][nt * 16 + fr] = f2bf(tau);
    }
  }
  __syncthreads();

  bf16x8 pa = *(const bf16x8*)&Ps[wave][fr][g * 8];
#pragma unroll
  for (int ct = 0; ct < 4; ++ct) {
    bf16x8 vb = *(const bf16x8*)&Vt[ct * 16 + fr][rbase + g * 8];
    f32x4 m = __builtin_amdgcn_mfma_f32_16x16x32_bf16(pa, vb, (f32x4){0.f, 0.f, 0.f, 0.f}, 0, 0, 0);
#pragma unroll
    for (int reg = 0; reg < 4; ++reg) {
      int t = t0 + wave * 16 + g * 4 + reg;
      msg[(rowbase + t) * 1024 + (size_t)h * 64 + ct * 16 + fr] = f2bf(m[reg]);
    }
  }
}

// ---------------------------------------------------------------- LayerNorm: bf16 y in -> fp32 out
__global__ __launch_bounds__(256) void layernorm_b(const ushort* __restrict__ yb,
                                                   const float* __restrict__ gamma,
                                                   const float* __restrict__ beta,
                                                   float* __restrict__ out) {
  const int row = blockIdx.x;
  const ushort* p = yb + (size_t)row * D_MODEL;
  const int tid = threadIdx.x;
  ushort4 v4 = ((const ushort4*)p)[tid];
  float y0 = bf2f(v4.x), y1 = bf2f(v4.y), y2 = bf2f(v4.z), y3 = bf2f(v4.w);
  float s = y0 + y1 + y2 + y3;
  float s2 = y0 * y0 + y1 * y1 + y2 * y2 + y3 * y3;
#pragma unroll
  for (int m = 1; m < 64; m <<= 1) {
    s += __shfl_xor(s, m);
    s2 += __shfl_xor(s2, m);
  }
  __shared__ float red[8];
  const int wave = tid >> 6, lane = tid & 63;
  if (lane == 0) { red[wave] = s; red[4 + wave] = s2; }
  __syncthreads();
  s = red[0] + red[1] + red[2] + red[3];
  s2 = red[4] + red[5] + red[6] + red[7];
  const float mu = s * (1.f / D_MODEL);
  const float var = s2 * (1.f / D_MODEL) - mu * mu;
  const float rstd = rsqrtf(var + 1e-5f);
  float4 g = *(const float4*)&gamma[tid * 4];
  float4 be = *(const float4*)&beta[tid * 4];
  float4 o;
  o.x = (y0 - mu) * rstd * g.x + be.x;
  o.y = (y1 - mu) * rstd * g.y + be.y;
  o.z = (y2 - mu) * rstd * g.z + be.z;
  o.w = (y3 - mu) * rstd * g.w + be.w;
  *(float4*)&out[(size_t)row * D_MODEL + tid * 4] = o;
}

// ---------------------------------------------------------------- launch
extern "C" void kernel_launch(void* const* d_in, const int* in_sizes, int n_in,
                              void* d_out, int out_size, void* d_ws, size_t ws_size,
                              hipStream_t stream) {
  (void)in_sizes; (void)n_in; (void)out_size; (void)ws_size;
  const float* x = (const float*)d_in[0];
  const float* wq = (const float*)d_in[1];
  const float* wkv = (const float*)d_in[2];
  const float* wo = (const float*)d_in[3];
  const float* gamma = (const float*)d_in[4];
  const float* beta = (const float*)d_in[5];
  float* out = (float*)d_out;

  ushort* xb = (ushort*)d_ws;                          // 8192x1024 bf16
  ushort* wb = xb + (size_t)8192 * 1024;               // 4096x1024: [wq;wkv;wo]
  ushort* qkvb = wb + (size_t)4096 * 1024;             // 8192x3072 (dead after attn)
  ushort* msgb = qkvb + (size_t)8192 * 3072;           // 8192x1024
  ushort* yb = qkvb;                                   // aliases qkvb (safe: attn done)

  const int M = NBATCH * SEQ_T;  // 8192

  (void)hipFuncSetAttribute(reinterpret_cast<const void*>(&gemm1_8w2b),
                            hipFuncAttributeMaxDynamicSharedMemorySize, 81920);
  (void)hipFuncSetAttribute(reinterpret_cast<const void*>(&gemm2_2pc),
                            hipFuncAttributeMaxDynamicSharedMemorySize, 65536);

  // casts (x + all weights, one launch)
  cast_all<<<12288, 256, 0, stream>>>((const float4*)x, (const float4*)wq,
                                      (const float4*)wkv, (const float4*)wo, xb, wb);

  // GEMM1: qkv = x @ [wq;wkv]^T  (M=8192, N=3072, K=1024) -> 16x64 = 1024 blocks, 2/CU, 8 waves
  gemm1_8w2b<<<dim3(3072 / 192, M / 128), 512, 81920, stream>>>(xb, wb, qkvb, M, 3072, 1024);

  // windowed sigmoid attention -> msg (bf16)
  attn_win_mfma<<<dim3(SEQ_T / 64, NHEADS, NBATCH), 256, 0, stream>>>(qkvb, msgb);

  // GEMM2: y = bf16(msg @ wo^T + x)  -> yb (aliases qkvb), 8x64 = 512 blocks, 2/CU
  gemm2_2pc<<<dim3(1024 / 128, M / 128), 256, 65536, stream>>>(msgb, wb + (size_t)3072 * 1024,
                                                               xb, yb, M, 1024, 1024);

  // LayerNorm: yb (bf16) -> out (fp32)
  layernorm_b<<<M, 256, 0, stream>>>(yb, gamma, beta, out);
}

// Round 16
// 116.221 us; speedup vs baseline: 1.0124x; 1.0124x over previous
//
#include <hip/hip_runtime.h>
#include <hip/hip_bf16.h>

// Problem constants (B=2, T=4096, D=1024, H=16, HD=64, W=16)
#define D_MODEL 1024
#define SEQ_T   4096
#define NBATCH  2
#define NHEADS  16
#define HEAD_D  64
#define WIN     16

typedef __attribute__((ext_vector_type(8))) short bf16x8;           // MFMA A/B frag
typedef __attribute__((ext_vector_type(8))) unsigned short u16x8;   // 16B bf16 load
typedef __attribute__((ext_vector_type(4))) float f32x4;            // MFMA C/D frag

__device__ __forceinline__ unsigned short f2bf(float f) {
  union { float f; unsigned int u; } v; v.f = f;
  unsigned int r = v.u + 0x7fffu + ((v.u >> 16) & 1u);  // RNE
  return (unsigned short)(r >> 16);
}
__device__ __forceinline__ float bf2f(unsigned short u) {
  union { unsigned int u; float f; } v; v.u = ((unsigned int)u) << 16;
  return v.f;
}

#define SBAR() __builtin_amdgcn_s_barrier()
#define LGKM0() asm volatile("s_waitcnt lgkmcnt(0)" ::: "memory")
#define LGKM8() asm volatile("s_waitcnt lgkmcnt(8)" ::: "memory")
#define VMC(n) asm volatile("s_waitcnt vmcnt(" #n ")" ::: "memory")

// ---------------------------------------------------------------- merged cast kernel
__global__ __launch_bounds__(256) void cast_all(const float4* __restrict__ x,
                                                const float4* __restrict__ wq,
                                                const float4* __restrict__ wkv,
                                                const float4* __restrict__ wo,
                                                ushort* __restrict__ xb,
                                                ushort* __restrict__ wb) {
  int i = blockIdx.x * 256 + threadIdx.x;  // 0..3145727 float4 units
  float4 v;
  ushort* dst;
  if (i < 2097152) {
    v = x[i];
    dst = xb + (size_t)i * 4;
  } else {
    int j = i - 2097152;  // 0..1048575
    const float4* src;
    int off;
    if (j < 262144) { src = wq; off = 0; }
    else if (j < 786432) { src = wkv; off = 262144; }
    else { src = wo; off = 786432; }
    v = src[j - off];
    dst = wb + (size_t)j * 4;
  }
  ushort4 o;
  o.x = f2bf(v.x); o.y = f2bf(v.y); o.z = f2bf(v.z); o.w = f2bf(v.w);
  *(ushort4*)dst = o;
}

// ---------------------------------------------------------------- GEMM1: 128x192, 4 waves, 2 blocks/CU
// (R13/R14 winner — session-best. 55.3 µs, 930 TF, conflicts 0.)
// Grid 16x64 = 1024 blocks = 2.0 rounds @ 2/CU. Per-wave 64x96 (acc[4][6]).
// LDS 80KiB: A[2][128][64] @0, B[2][192][64] @32KiB. Chunk-XOR swizzle both-sides.
// 3 phases/K-tile, one stage unit per phase after its region's last reader; vmcnt(4) at p3.
__global__ __launch_bounds__(256, 2) void gemm1_2pc(const ushort* __restrict__ A,
                                                    const ushort* __restrict__ Bt,
                                                    ushort* __restrict__ C,
                                                    int M, int N, int K) {
  extern __shared__ char smem[];  // 81920 bytes
  const int NTK = K >> 6;
  const int tid = threadIdx.x;
  const int wid = tid >> 6;   // 0..3
  const int lane = tid & 63;
  const int lin = blockIdx.y * 16 + blockIdx.x;     // 0..1023
  const int swz = (lin & 7) * 128 + (lin >> 3);     // bijective (1024 % 8 == 0)
  const int m0 = (swz >> 4) * 128;
  const int n0 = (swz & 15) * 192;

  const int l8 = lane >> 3;
  const int lchunk = (lane & 7) ^ (l8 & 7);
  const ushort* pA = A + (size_t)(m0 + wid * 8 + l8) * K + lchunk * 8;
  const ushort* pB = Bt + (size_t)(n0 + wid * 8 + l8) * K + lchunk * 8;

#define SA(kt, db)                                                                         \
  {                                                                                        \
    _Pragma("unroll") for (int j = 0; j < 4; ++j) {                                        \
      const ushort* gp = pA + (size_t)(j * 32) * K + (size_t)(kt) * 64;                    \
      char* lp = smem + (db) * 16384 + (j * 4 + wid) * 1024;                               \
      __builtin_amdgcn_global_load_lds((const __attribute__((address_space(1))) void*)gp,  \
                                       (__attribute__((address_space(3))) void*)lp, 16, 0, 0); \
    }                                                                                      \
  }
#define SB(kt, db, j0)                                                                     \
  {                                                                                        \
    _Pragma("unroll") for (int j = (j0); j < (j0) + 3; ++j) {                              \
      const ushort* gp = pB + (size_t)(j * 32) * K + (size_t)(kt) * 64;                    \
      char* lp = smem + 32768 + (db) * 24576 + (j * 4 + wid) * 1024;                       \
      __builtin_amdgcn_global_load_lds((const __attribute__((address_space(1))) void*)gp,  \
                                       (__attribute__((address_space(3))) void*)lp, 16, 0, 0); \
    }                                                                                      \
  }

  const int fr = lane & 15;
  const int g = lane >> 4;
  const int wr = wid >> 1;   // 0..1
  const int wc = wid & 1;    // 0..1
  int aRow[4], bRow[6], ch[2];
#pragma unroll
  for (int mi = 0; mi < 4; ++mi) aRow[mi] = (wr * 64 + mi * 16 + fr) * 128;
#pragma unroll
  for (int j = 0; j < 6; ++j) bRow[j] = (wc * 96 + j * 16 + fr) * 128;
#pragma unroll
  for (int kk = 0; kk < 2; ++kk) ch[kk] = ((kk * 4 + g) ^ (fr & 7)) * 16;

  f32x4 acc[4][6];
#pragma unroll
  for (int mi = 0; mi < 4; ++mi)
#pragma unroll
    for (int j = 0; j < 6; ++j) acc[mi][j] = (f32x4){0.f, 0.f, 0.f, 0.f};

  bf16x8 a[4][2], b[2][2];

#define RD_A(db)                                                               \
  _Pragma("unroll") for (int mi = 0; mi < 4; ++mi)                             \
    _Pragma("unroll") for (int kk = 0; kk < 2; ++kk)                           \
      a[mi][kk] = *(const bf16x8*)(smem + (db) * 16384 + aRow[mi] + ch[kk]);
#define RD_B(db, nh)                                                           \
  _Pragma("unroll") for (int ni = 0; ni < 2; ++ni)                             \
    _Pragma("unroll") for (int kk = 0; kk < 2; ++kk)                           \
      b[ni][kk] = *(const bf16x8*)(smem + 32768 + (db) * 24576 +               \
                                   bRow[(nh) * 2 + ni] + ch[kk]);
#define MM(nh)                                                                 \
  __builtin_amdgcn_s_setprio(1);                                               \
  _Pragma("unroll") for (int kk = 0; kk < 2; ++kk)                             \
    _Pragma("unroll") for (int mi = 0; mi < 4; ++mi)                           \
      _Pragma("unroll") for (int ni = 0; ni < 2; ++ni)                         \
        acc[mi][(nh) * 2 + ni] = __builtin_amdgcn_mfma_f32_16x16x32_bf16(      \
            a[mi][kk], b[ni][kk], acc[mi][(nh) * 2 + ni], 0, 0, 0);            \
  __builtin_amdgcn_s_setprio(0);

  SA(0, 0); SB(0, 0, 0); SB(0, 0, 3); SA(1, 1);
  VMC(4);
  SBAR();

#pragma unroll 1
  for (int t = 0; t < NTK; ++t) {
    const int db = t & 1;
    const int t1 = (t + 1 < NTK) ? t + 1 : NTK - 1;
    const int t2 = (t + 2 < NTK) ? t + 2 : NTK - 1;
    const int d1 = t1 & 1, d2 = t2 & 1;

    RD_A(db); RD_B(db, 0);
    SB(t1, d1, 0);
    LGKM8();
    SBAR(); LGKM0();
    MM(0);
    SBAR();

    RD_B(db, 1);
    SB(t1, d1, 3);
    SBAR(); LGKM0();
    MM(1);
    SBAR();

    RD_B(db, 2);
    SA(t2, d2);
    VMC(4);
    SBAR(); LGKM0();
    MM(2);
    SBAR();
  }

  const int cc = lane & 15;
  const int cr4 = (lane >> 4) * 4;
#pragma unroll
  for (int mi = 0; mi < 4; ++mi)
#pragma unroll
    for (int j = 0; j < 6; ++j)
#pragma unroll
      for (int r = 0; r < 4; ++r) {
        int row = m0 + wr * 64 + mi * 16 + cr4 + r;
        int col = n0 + wc * 96 + j * 16 + cc;
        C[(size_t)row * N + col] = f2bf(acc[mi][j][r]);
      }
#undef SA
#undef SB
#undef RD_A
#undef RD_B
#undef MM
}

// ---------------------------------------------------------------- GEMM2: 128x128, 4 waves, 2 blocks/CU
// (R14 — unchanged.)
__global__ __launch_bounds__(256, 2) void gemm2_2pc(const ushort* __restrict__ A,
                                                    const ushort* __restrict__ Bt,
                                                    const ushort* __restrict__ residb,
                                                    ushort* __restrict__ Yb,
                                                    int M, int N, int K) {
  extern __shared__ char smem[];  // 65536 bytes
  const int NTK = K >> 6;
  const int tid = threadIdx.x;
  const int wid = tid >> 6;   // 0..3
  const int lane = tid & 63;
  const int lin = blockIdx.y * 8 + blockIdx.x;      // 0..511
  const int swz = (lin & 7) * 64 + (lin >> 3);      // bijective (512 % 8 == 0)
  const int m0 = (swz >> 3) * 128;
  const int n0 = (swz & 7) * 128;

  const int l8 = lane >> 3;
  const int lchunk = (lane & 7) ^ (l8 & 7);
  const ushort* pA = A + (size_t)(m0 + wid * 8 + l8) * K + lchunk * 8;
  const ushort* pB = Bt + (size_t)(n0 + wid * 8 + l8) * K + lchunk * 8;

#define SA2(kt, db)                                                                        \
  {                                                                                        \
    _Pragma("unroll") for (int j = 0; j < 4; ++j) {                                        \
      const ushort* gp = pA + (size_t)(j * 32) * K + (size_t)(kt) * 64;                    \
      char* lp = smem + (db) * 16384 + (j * 4 + wid) * 1024;                               \
      __builtin_amdgcn_global_load_lds((const __attribute__((address_space(1))) void*)gp,  \
                                       (__attribute__((address_space(3))) void*)lp, 16, 0, 0); \
    }                                                                                      \
  }
#define SB2(kt, db)                                                                        \
  {                                                                                        \
    _Pragma("unroll") for (int j = 0; j < 4; ++j) {                                        \
      const ushort* gp = pB + (size_t)(j * 32) * K + (size_t)(kt) * 64;                    \
      char* lp = smem + 32768 + (db) * 16384 + (j * 4 + wid) * 1024;                       \
      __builtin_amdgcn_global_load_lds((const __attribute__((address_space(1))) void*)gp,  \
                                       (__attribute__((address_space(3))) void*)lp, 16, 0, 0); \
    }                                                                                      \
  }

  const int fr = lane & 15;
  const int g = lane >> 4;
  const int wr = wid >> 1;   // 0..1
  const int wc = wid & 1;    // 0..1
  int aRow[4], bRow[4], ch[2];
#pragma unroll
  for (int mi = 0; mi < 4; ++mi) aRow[mi] = (wr * 64 + mi * 16 + fr) * 128;
#pragma unroll
  for (int j = 0; j < 4; ++j) bRow[j] = (wc * 64 + j * 16 + fr) * 128;
#pragma unroll
  for (int kk = 0; kk < 2; ++kk) ch[kk] = ((kk * 4 + g) ^ (fr & 7)) * 16;

  f32x4 acc[4][4];
#pragma unroll
  for (int mi = 0; mi < 4; ++mi)
#pragma unroll
    for (int j = 0; j < 4; ++j) acc[mi][j] = (f32x4){0.f, 0.f, 0.f, 0.f};

  bf16x8 a[4][2], b[2][2];

#define RD_A2(db)                                                              \
  _Pragma("unroll") for (int mi = 0; mi < 4; ++mi)                             \
    _Pragma("unroll") for (int kk = 0; kk < 2; ++kk)                           \
      a[mi][kk] = *(const bf16x8*)(smem + (db) * 16384 + aRow[mi] + ch[kk]);
#define RD_B2(db, nh)                                                          \
  _Pragma("unroll") for (int ni = 0; ni < 2; ++ni)                             \
    _Pragma("unroll") for (int kk = 0; kk < 2; ++kk)                           \
      b[ni][kk] = *(const bf16x8*)(smem + 32768 + (db) * 16384 +               \
                                   bRow[(nh) * 2 + ni] + ch[kk]);
#define MM2(nh)                                                                \
  __builtin_amdgcn_s_setprio(1);                                               \
  _Pragma("unroll") for (int kk = 0; kk < 2; ++kk)                             \
    _Pragma("unroll") for (int mi = 0; mi < 4; ++mi)                           \
      _Pragma("unroll") for (int ni = 0; ni < 2; ++ni)                         \
        acc[mi][(nh) * 2 + ni] = __builtin_amdgcn_mfma_f32_16x16x32_bf16(      \
            a[mi][kk], b[ni][kk], acc[mi][(nh) * 2 + ni], 0, 0, 0);            \
  __builtin_amdgcn_s_setprio(0);

  SA2(0, 0); SB2(0, 0); SA2(1, 1);
  VMC(4);
  SBAR();

#pragma unroll 1
  for (int t = 0; t < NTK; ++t) {
    const int db = t & 1;
    const int t1 = (t + 1 < NTK) ? t + 1 : NTK - 1;
    const int t2 = (t + 2 < NTK) ? t + 2 : NTK - 1;
    const int d1 = t1 & 1, d2 = t2 & 1;

    RD_A2(db); RD_B2(db, 0);
    SB2(t1, d1);
    LGKM8();
    SBAR(); LGKM0();
    MM2(0);
    SBAR();

    RD_B2(db, 1);
    SA2(t2, d2);
    VMC(4);
    SBAR(); LGKM0();
    MM2(1);
    SBAR();
  }

  const int cc = lane & 15;
  const int cr4 = (lane >> 4) * 4;
#pragma unroll
  for (int mi = 0; mi < 4; ++mi)
#pragma unroll
    for (int j = 0; j < 4; ++j)
#pragma unroll
      for (int r = 0; r < 4; ++r) {
        int row = m0 + wr * 64 + mi * 16 + cr4 + r;
        int col = n0 + wc * 64 + j * 16 + cc;
        size_t idx = (size_t)row * N + col;
        Yb[idx] = f2bf(acc[mi][j][r] + bf2f(residb[idx]));
      }
#undef SA2
#undef SB2
#undef RD_A2
#undef RD_B2
#undef MM2
}

// ---------------------------------------------------------------- sliding-window attention (MFMA band)
__global__ __launch_bounds__(256) void attn_win_mfma(const ushort* __restrict__ qkv,
                                                     ushort* __restrict__ msg) {
  __shared__ ushort Ks[80][72];
  __shared__ ushort Vt[64][88];
  __shared__ ushort Ps[4][16][40];

  const int tile = blockIdx.x;
  const int h = blockIdx.y;
  const int b = blockIdx.z;
  const int t0 = tile * 64;
  const size_t rowbase = (size_t)b * SEQ_T;
  const int tid = threadIdx.x;
  const int wave = tid >> 6;
  const int lane = tid & 63;

  for (int chunk = tid; chunk < 1280; chunk += 256) {
    int r = chunk >> 4;
    int c = (chunk & 15) * 8;
    int t = t0 - 16 + r;
    u16x8 u = {0, 0, 0, 0, 0, 0, 0, 0};
    if (t >= 0)
      u = *(const u16x8*)(qkv + (rowbase + t) * 3072 + 1024 + (size_t)h * 128 + c);
    if (c < 64) {
      *(u16x8*)&Ks[r][c] = u;
    } else {
      int d0 = c - 64;
#pragma unroll
      for (int j = 0; j < 8; ++j) Vt[d0 + j][r] = u[j];
    }
  }
  __syncthreads();

  const int fr = lane & 15;
  const int g = lane >> 4;
  const int rbase = wave * 16;

  bf16x8 qa[2];
#pragma unroll
  for (int kk = 0; kk < 2; ++kk)
    qa[kk] = *(const bf16x8*)(qkv + (rowbase + t0 + wave * 16 + fr) * 3072 +
                              (size_t)h * 64 + kk * 32 + g * 8);

  f32x4 sacc[2];
  sacc[0] = (f32x4){0.f, 0.f, 0.f, 0.f};
  sacc[1] = (f32x4){0.f, 0.f, 0.f, 0.f};
#pragma unroll
  for (int kk = 0; kk < 2; ++kk) {
#pragma unroll
    for (int nt = 0; nt < 2; ++nt) {
      bf16x8 kb = *(const bf16x8*)&Ks[rbase + nt * 16 + fr][kk * 32 + g * 8];
      sacc[nt] = __builtin_amdgcn_mfma_f32_16x16x32_bf16(qa[kk], kb, sacc[nt], 0, 0, 0);
    }
  }

#pragma unroll
  for (int nt = 0; nt < 2; ++nt) {
    int tk = t0 - 16 + rbase + nt * 16 + fr;
#pragma unroll
    for (int reg = 0; reg < 4; ++reg) {
      int t = t0 + wave * 16 + g * 4 + reg;
      float tau = 0.f;
      if (tk >= 0 && tk >= t - WIN && tk <= t - 1)
        tau = 1.f / (1.f + __expf(-sacc[nt][reg] * 0.125f));
      Ps[wave][g * 4 + reg][nt * 16 + fr] = f2bf(tau);
    }
  }
  __syncthreads();

  bf16x8 pa = *(const bf16x8*)&Ps[wave][fr][g * 8];
#pragma unroll
  for (int ct = 0; ct < 4; ++ct) {
    bf16x8 vb = *(const bf16x8*)&Vt[ct * 16 + fr][rbase + g * 8];
    f32x4 m = __builtin_amdgcn_mfma_f32_16x16x32_bf16(pa, vb, (f32x4){0.f, 0.f, 0.f, 0.f}, 0, 0, 0);
#pragma unroll
    for (int reg = 0; reg < 4; ++reg) {
      int t = t0 + wave * 16 + g * 4 + reg;
      msg[(rowbase + t) * 1024 + (size_t)h * 64 + ct * 16 + fr] = f2bf(m[reg]);
    }
  }
}

// ---------------------------------------------------------------- LayerNorm: bf16 y in -> fp32 out
__global__ __launch_bounds__(256) void layernorm_b(const ushort* __restrict__ yb,
                                                   const float* __restrict__ gamma,
                                                   const float* __restrict__ beta,
                                                   float* __restrict__ out) {
  const int row = blockIdx.x;
  const ushort* p = yb + (size_t)row * D_MODEL;
  const int tid = threadIdx.x;
  ushort4 v4 = ((const ushort4*)p)[tid];
  float y0 = bf2f(v4.x), y1 = bf2f(v4.y), y2 = bf2f(v4.z), y3 = bf2f(v4.w);
  float s = y0 + y1 + y2 + y3;
  float s2 = y0 * y0 + y1 * y1 + y2 * y2 + y3 * y3;
#pragma unroll
  for (int m = 1; m < 64; m <<= 1) {
    s += __shfl_xor(s, m);
    s2 += __shfl_xor(s2, m);
  }
  __shared__ float red[8];
  const int wave = tid >> 6, lane = tid & 63;
  if (lane == 0) { red[wave] = s; red[4 + wave] = s2; }
  __syncthreads();
  s = red[0] + red[1] + red[2] + red[3];
  s2 = red[4] + red[5] + red[6] + red[7];
  const float mu = s * (1.f / D_MODEL);
  const float var = s2 * (1.f / D_MODEL) - mu * mu;
  const float rstd = rsqrtf(var + 1e-5f);
  float4 g = *(const float4*)&gamma[tid * 4];
  float4 be = *(const float4*)&beta[tid * 4];
  float4 o;
  o.x = (y0 - mu) * rstd * g.x + be.x;
  o.y = (y1 - mu) * rstd * g.y + be.y;
  o.z = (y2 - mu) * rstd * g.z + be.z;
  o.w = (y3 - mu) * rstd * g.w + be.w;
  *(float4*)&out[(size_t)row * D_MODEL + tid * 4] = o;
}

// ---------------------------------------------------------------- launch
extern "C" void kernel_launch(void* const* d_in, const int* in_sizes, int n_in,
                              void* d_out, int out_size, void* d_ws, size_t ws_size,
                              hipStream_t stream) {
  (void)in_sizes; (void)n_in; (void)out_size; (void)ws_size;
  const float* x = (const float*)d_in[0];
  const float* wq = (const float*)d_in[1];
  const float* wkv = (const float*)d_in[2];
  const float* wo = (const float*)d_in[3];
  const float* gamma = (const float*)d_in[4];
  const float* beta = (const float*)d_in[5];
  float* out = (float*)d_out;

  ushort* xb = (ushort*)d_ws;                          // 8192x1024 bf16
  ushort* wb = xb + (size_t)8192 * 1024;               // 4096x1024: [wq;wkv;wo]
  ushort* qkvb = wb + (size_t)4096 * 1024;             // 8192x3072 (dead after attn)
  ushort* msgb = qkvb + (size_t)8192 * 3072;           // 8192x1024
  ushort* yb = qkvb;                                   // aliases qkvb (safe: attn done)

  const int M = NBATCH * SEQ_T;  // 8192

  (void)hipFuncSetAttribute(reinterpret_cast<const void*>(&gemm1_2pc),
                            hipFuncAttributeMaxDynamicSharedMemorySize, 81920);
  (void)hipFuncSetAttribute(reinterpret_cast<const void*>(&gemm2_2pc),
                            hipFuncAttributeMaxDynamicSharedMemorySize, 65536);

  // casts (x + all weights, one launch)
  cast_all<<<12288, 256, 0, stream>>>((const float4*)x, (const float4*)wq,
                                      (const float4*)wkv, (const float4*)wo, xb, wb);

  // GEMM1: qkv = x @ [wq;wkv]^T  (M=8192, N=3072, K=1024) -> 16x64 = 1024 blocks, 2/CU
  gemm1_2pc<<<dim3(3072 / 192, M / 128), 256, 81920, stream>>>(xb, wb, qkvb, M, 3072, 1024);

  // windowed sigmoid attention -> msg (bf16)
  attn_win_mfma<<<dim3(SEQ_T / 64, NHEADS, NBATCH), 256, 0, stream>>>(qkvb, msgb);

  // GEMM2: y = bf16(msg @ wo^T + x)  -> yb (aliases qkvb), 8x64 = 512 blocks, 2/CU
  gemm2_2pc<<<dim3(1024 / 128, M / 128), 256, 65536, stream>>>(msgb, wb + (size_t)3072 * 1024,
                                                               xb, yb, M, 1024, 1024);

  // LayerNorm: yb (bf16) -> out (fp32)
  layernorm_b<<<M, 256, 0, stream>>>(yb, gamma, beta, out);
}